// Round 1
// baseline (934.869 us; speedup 1.0000x reference)
//
#include <hip/hip_runtime.h>
#include <stdint.h>
#include <stddef.h>

// Problem: AdaConv2d  B=8 C=256 H=W=128 G=32 CPG=8 K=3 OUT=256
// Pipeline: instance-norm -> per-sample adaptive grouped 3x3 (+1x1 grouped +bias)
//           -> static 3x3 conv 256->256, reflect padding everywhere.
//
// Stage fusion: z = pointwise(spatial(xn)) + bias collapses to ONE grouped 3x3
// with weff[b,c,i,t] = sum_j wp[b,c,j] * ws[b, g*8+j, i, t].
// Final conv done as bf16 MFMA implicit GEMM (M=pixels, N=oc, K=c*9).

typedef __attribute__((ext_vector_type(8))) short   s16x8;  // 8 bf16 in 4 VGPRs
typedef __attribute__((ext_vector_type(4))) float   f32x4;

#define NB   8
#define NC   256
#define NH   128
#define NW   128
#define NG   32
#define CPG  8
#define NOUT 256
#define HWPLANE (NH*NW)          // 16384

__device__ __forceinline__ unsigned short f2bf(float f) {
    union { float f; unsigned u; } v; v.f = f;
    unsigned u = v.u;
    u += 0x7fffu + ((u >> 16) & 1u);   // RNE
    return (unsigned short)(u >> 16);
}

__device__ __forceinline__ int refl128(int i) {
    return i < 0 ? 1 : (i > 127 ? 126 : i);
}

// ---------------------------------------------------------------- stats
// one block per (b,c): mean and rstd over the 128x128 plane (biased var)
__global__ __launch_bounds__(256) void stats_k(const float* __restrict__ x,
                                               float* __restrict__ stats) {
    int bc = blockIdx.x, t = threadIdx.x;
    const float4* p = (const float4*)(x + (size_t)bc * HWPLANE);
    float s = 0.f, q = 0.f;
#pragma unroll
    for (int k = 0; k < 16; ++k) {
        float4 v = p[k * 256 + t];
        s += v.x + v.y + v.z + v.w;
        q += v.x * v.x + v.y * v.y + v.z * v.z + v.w * v.w;
    }
    __shared__ float ss[256], sq[256];
    ss[t] = s; sq[t] = q;
    __syncthreads();
    for (int o = 128; o > 0; o >>= 1) {
        if (t < o) { ss[t] += ss[t + o]; sq[t] += sq[t + o]; }
        __syncthreads();
    }
    if (t == 0) {
        float mean = ss[0] * (1.f / HWPLANE);
        float var  = sq[0] * (1.f / HWPLANE) - mean * mean;
        stats[bc * 2]     = mean;
        stats[bc * 2 + 1] = rsqrtf(var + 1e-5f);
    }
}

// ---------------------------------------------------------------- weff
// weff[b,c,i,t] = sum_j wp[b,c,j] * ws[b, g*8+j, i, t];  one thread each
__global__ __launch_bounds__(256) void weff_k(const float* __restrict__ wsp,
                                              const float* __restrict__ wpw,
                                              float* __restrict__ weff) {
    int tid = blockIdx.x * 256 + threadIdx.x;           // 147456 total, exact
    int e  = tid % 72;
    int bc = tid / 72;
    int c = bc & 255, b = bc >> 8, g = c >> 3;
    int i = e / 9, t = e - i * 9;
    float acc = 0.f;
#pragma unroll
    for (int j = 0; j < 8; ++j)
        acc += wpw[bc * 8 + j] * wsp[(((b * NC + g * 8 + j) * CPG) + i) * 9 + t];
    weff[(size_t)bc * 72 + e] = acc;
}

// ---------------------------------------------------------------- weight repack
// conv_w [O][C][3][3] fp32  ->  wtT [tap][O][C] bf16  (B-operand friendly)
__global__ __launch_bounds__(256) void repack_k(const float* __restrict__ cw,
                                                unsigned short* __restrict__ wtT) {
    int tid = blockIdx.x * 256 + threadIdx.x;           // 589824 total, exact
    int c = tid & 255;
    int o = (tid >> 8) & 255;
    int t = tid >> 16;                                  // 0..8
    float v = cw[(size_t)(o * NC + c) * 9 + t];
    wtT[((size_t)t * NOUT + o) * NC + c] = f2bf(v);
}

// ---------------------------------------------------------------- fused norm + adaptive conv
// block = (b, g, h): all 128 w, 8 output channels of the group.
// z written channels-last [B][H][W][C] bf16 (A-operand friendly for MFMA).
__global__ __launch_bounds__(128) void ada_k(const float* __restrict__ x,
                                             const float* __restrict__ stats,
                                             const float* __restrict__ weff,
                                             const float* __restrict__ bias,
                                             unsigned short* __restrict__ z) {
    int bx = blockIdx.x;
    int h = bx & 127;
    int g = (bx >> 7) & 31;
    int b = bx >> 12;
    int w = threadIdx.x;

    __shared__ float sx[CPG][3][NW];       // normalized input rows, 12 KB
#pragma unroll
    for (int ic = 0; ic < CPG; ++ic) {
        int cg = g * 8 + ic;
        float mean = stats[(b * NC + cg) * 2];
        float rstd = stats[(b * NC + cg) * 2 + 1];
        const float* xp = x + (size_t)(b * NC + cg) * HWPLANE;
#pragma unroll
        for (int dh = 0; dh < 3; ++dh) {
            int r = refl128(h + dh - 1);
            sx[ic][dh][w] = (xp[r * NW + w] - mean) * rstd;
        }
    }
    __syncthreads();

    float acc[CPG];
    const float* bp = bias + b * NC + g * 8;
#pragma unroll
    for (int c = 0; c < CPG; ++c) acc[c] = bp[c];

    // block-uniform weight pointer -> compiler emits scalar (SGPR) loads
    const float* wp = weff + (size_t)(b * NC + g * 8) * 72;
    int wm = (w == 0) ? 1 : w - 1;
    int wq = (w == 127) ? 126 : w + 1;

#pragma unroll
    for (int ic = 0; ic < CPG; ++ic) {
        float xv[9];
#pragma unroll
        for (int dh = 0; dh < 3; ++dh) {
            xv[dh * 3 + 0] = sx[ic][dh][wm];
            xv[dh * 3 + 1] = sx[ic][dh][w];
            xv[dh * 3 + 2] = sx[ic][dh][wq];
        }
#pragma unroll
        for (int c = 0; c < CPG; ++c)
#pragma unroll
            for (int t = 0; t < 9; ++t)
                acc[c] += wp[c * 72 + ic * 9 + t] * xv[t];
    }

    unsigned short ob[8];
#pragma unroll
    for (int c = 0; c < CPG; ++c) ob[c] = f2bf(acc[c]);
    uint4 pk;
    pk.x = (unsigned)ob[0] | ((unsigned)ob[1] << 16);
    pk.y = (unsigned)ob[2] | ((unsigned)ob[3] << 16);
    pk.z = (unsigned)ob[4] | ((unsigned)ob[5] << 16);
    pk.w = (unsigned)ob[6] | ((unsigned)ob[7] << 16);
    *(uint4*)(z + ((size_t)((b * NH + h) * NW + w)) * NC + g * 8) = pk;
}

// ---------------------------------------------------------------- final conv (MFMA implicit GEMM)
// grid: 2048 blocks = (b,h) x 2 oc-halves. block 256 thr = 4 waves, each 64x64.
// out[w][oc] = sum_{t,c} z[b, r(dh), refl(w+dw-1), c] * wtT[t][oc][c] + conv_b
__global__ __launch_bounds__(256) void final_k(const unsigned short* __restrict__ z,
                                               const unsigned short* __restrict__ wtT,
                                               const float* __restrict__ cb,
                                               float* __restrict__ out) {
    int bx = blockIdx.x;
    int nb = bx & 1;            // oc half
    int bh = bx >> 1;
    int b = bh >> 7;
    int h = bh & 127;

    int tid  = threadIdx.x;
    int wv   = tid >> 6;
    int lane = tid & 63;
    int l15  = lane & 15;
    int quad = lane >> 4;
    int m_off = (wv & 1) << 6;              // 0 / 64 in w
    int n0    = (nb << 7) + ((wv >> 1) << 6);  // oc base of this wave's 64

    f32x4 acc[4][4] = {};

    for (int t = 0; t < 9; ++t) {
        int dh = t / 3, dw = t - dh * 3;
        int r = refl128(h + dh - 1);
        const unsigned short* zrow = z + (size_t)((b * NH + r) * NW) * NC;

        const s16x8* ap[4];
#pragma unroll
        for (int i = 0; i < 4; ++i) {
            int wi = refl128(m_off + 16 * i + l15 + dw - 1);
            ap[i] = (const s16x8*)(zrow + wi * NC + quad * 8);
        }
        const s16x8* bpv[4];
#pragma unroll
        for (int j = 0; j < 4; ++j) {
            int oc = n0 + 16 * j + l15;
            bpv[j] = (const s16x8*)(wtT + ((size_t)t * NOUT + oc) * NC + quad * 8);
        }
#pragma unroll
        for (int k = 0; k < 8; ++k) {
            s16x8 av[4], bv[4];
#pragma unroll
            for (int i = 0; i < 4; ++i) av[i] = ap[i][k * 4];
#pragma unroll
            for (int j = 0; j < 4; ++j) bv[j] = bpv[j][k * 4];
#pragma unroll
            for (int i = 0; i < 4; ++i)
#pragma unroll
                for (int j = 0; j < 4; ++j)
                    acc[i][j] = __builtin_amdgcn_mfma_f32_16x16x32_bf16(
                        av[i], bv[j], acc[i][j], 0, 0, 0);
        }
    }

    // epilogue: D layout col=lane&15, row=quad*4+reg -> pack 4 consecutive w
#pragma unroll
    for (int j = 0; j < 4; ++j) {
        int oc = n0 + 16 * j + l15;
        float bvl = cb[oc];
#pragma unroll
        for (int i = 0; i < 4; ++i) {
            int w0 = m_off + 16 * i + quad * 4;
            float* dst = out + (((size_t)(b * NOUT + oc) * NH + h) * NW + w0);
            f32x4 v = acc[i][j];
            float4 o4 = { v[0] + bvl, v[1] + bvl, v[2] + bvl, v[3] + bvl };
            *(float4*)dst = o4;
        }
    }
}

// ---------------------------------------------------------------- launch
extern "C" void kernel_launch(void* const* d_in, const int* in_sizes, int n_in,
                              void* d_out, int out_size, void* d_ws, size_t ws_size,
                              hipStream_t stream) {
    const float* x   = (const float*)d_in[0];
    const float* wsp = (const float*)d_in[1];
    const float* wpw = (const float*)d_in[2];
    const float* bia = (const float*)d_in[3];
    const float* cw  = (const float*)d_in[4];
    const float* cb  = (const float*)d_in[5];
    float* out = (float*)d_out;

    // workspace layout (all 256B aligned):
    //   stats 16 KB | weff 576 KB | wtT 1.13 MB | z 64 MB   (total ~65.7 MB)
    char* ws = (char*)d_ws;
    float*          stats = (float*)ws;                          // 2048*2 f32
    float*          weff  = (float*)(ws + 16384);                // 2048*72 f32
    unsigned short* wtT   = (unsigned short*)(ws + 606208);      // 9*256*256 bf16
    unsigned short* z     = (unsigned short*)(ws + 1785856);     // 8*128*128*256 bf16

    stats_k <<<NB * NC, 256, 0, stream>>>(x, stats);
    weff_k  <<<576,     256, 0, stream>>>(wsp, wpw, weff);
    repack_k<<<2304,    256, 0, stream>>>(cw, wtT);
    ada_k   <<<NB * NG * NH, 128, 0, stream>>>(x, stats, weff, bia, z);
    final_k <<<NB * NH * 2,  256, 0, stream>>>(z, wtT, cb, out);
}

// Round 2
// 501.172 us; speedup vs baseline: 1.8654x; 1.8654x over previous
//
#include <hip/hip_runtime.h>
#include <stdint.h>
#include <stddef.h>

// Problem: AdaConv2d  B=8 C=256 H=W=128 G=32 CPG=8 K=3 OUT=256
// Pipeline: instance-norm -> per-sample adaptive grouped 3x3 (+1x1 grouped +bias)
//           -> static 3x3 conv 256->256, reflect padding everywhere.
//
// final conv = bf16 MFMA implicit GEMM, LDS-tiled (m97 structure):
//   block = 128 w x 128 oc, BK=64, A staged per (dh,kc), B double-buffered per tap.
//   global_load_lds width=16 with XOR-swizzled gather so ds_read_b128 is ~conflict-free.

typedef __attribute__((ext_vector_type(8))) short   s16x8;  // 8 bf16 in 4 VGPRs
typedef __attribute__((ext_vector_type(4))) float   f32x4;

#define NB   8
#define NC   256
#define NH   128
#define NW   128
#define NG   32
#define CPG  8
#define NOUT 256
#define HWPLANE (NH*NW)          // 16384

__device__ __forceinline__ unsigned short f2bf(float f) {
    union { float f; unsigned u; } v; v.f = f;
    unsigned u = v.u;
    u += 0x7fffu + ((u >> 16) & 1u);   // RNE
    return (unsigned short)(u >> 16);
}

__device__ __forceinline__ int refl128(int i) {
    return i < 0 ? 1 : (i > 127 ? 126 : i);
}

__device__ __forceinline__ void async_load16(const void* g, void* l) {
    __builtin_amdgcn_global_load_lds(
        (const __attribute__((address_space(1))) unsigned int*)g,
        (__attribute__((address_space(3))) unsigned int*)l,
        16, 0, 0);
}

// ---------------------------------------------------------------- stats
__global__ __launch_bounds__(256) void stats_k(const float* __restrict__ x,
                                               float* __restrict__ stats) {
    int bc = blockIdx.x, t = threadIdx.x;
    const float4* p = (const float4*)(x + (size_t)bc * HWPLANE);
    float s = 0.f, q = 0.f;
#pragma unroll
    for (int k = 0; k < 16; ++k) {
        float4 v = p[k * 256 + t];
        s += v.x + v.y + v.z + v.w;
        q += v.x * v.x + v.y * v.y + v.z * v.z + v.w * v.w;
    }
    __shared__ float ss[256], sq[256];
    ss[t] = s; sq[t] = q;
    __syncthreads();
    for (int o = 128; o > 0; o >>= 1) {
        if (t < o) { ss[t] += ss[t + o]; sq[t] += sq[t + o]; }
        __syncthreads();
    }
    if (t == 0) {
        float mean = ss[0] * (1.f / HWPLANE);
        float var  = sq[0] * (1.f / HWPLANE) - mean * mean;
        stats[bc * 2]     = mean;
        stats[bc * 2 + 1] = rsqrtf(var + 1e-5f);
    }
}

// ---------------------------------------------------------------- weff
__global__ __launch_bounds__(256) void weff_k(const float* __restrict__ wsp,
                                              const float* __restrict__ wpw,
                                              float* __restrict__ weff) {
    int tid = blockIdx.x * 256 + threadIdx.x;           // 147456 total, exact
    int e  = tid % 72;
    int bc = tid / 72;
    int c = bc & 255, b = bc >> 8, g = c >> 3;
    int i = e / 9, t = e - i * 9;
    float acc = 0.f;
#pragma unroll
    for (int j = 0; j < 8; ++j)
        acc += wpw[bc * 8 + j] * wsp[(((b * NC + g * 8 + j) * CPG) + i) * 9 + t];
    weff[(size_t)bc * 72 + e] = acc;
}

// ---------------------------------------------------------------- weight repack
// conv_w [O][C][3][3] fp32  ->  wtT [tap][O][C] bf16
__global__ __launch_bounds__(256) void repack_k(const float* __restrict__ cw,
                                                unsigned short* __restrict__ wtT) {
    int tid = blockIdx.x * 256 + threadIdx.x;           // 589824 total, exact
    int c = tid & 255;
    int o = (tid >> 8) & 255;
    int t = tid >> 16;                                  // 0..8
    float v = cw[(size_t)(o * NC + c) * 9 + t];
    wtT[((size_t)t * NOUT + o) * NC + c] = f2bf(v);
}

// ---------------------------------------------------------------- fused norm + adaptive conv
__global__ __launch_bounds__(128) void ada_k(const float* __restrict__ x,
                                             const float* __restrict__ stats,
                                             const float* __restrict__ weff,
                                             const float* __restrict__ bias,
                                             unsigned short* __restrict__ z) {
    int bx = blockIdx.x;
    int h = bx & 127;
    int g = (bx >> 7) & 31;
    int b = bx >> 12;
    int w = threadIdx.x;

    __shared__ float sx[CPG][3][NW];       // normalized input rows, 12 KB
#pragma unroll
    for (int ic = 0; ic < CPG; ++ic) {
        int cg = g * 8 + ic;
        float mean = stats[(b * NC + cg) * 2];
        float rstd = stats[(b * NC + cg) * 2 + 1];
        const float* xp = x + (size_t)(b * NC + cg) * HWPLANE;
#pragma unroll
        for (int dh = 0; dh < 3; ++dh) {
            int r = refl128(h + dh - 1);
            sx[ic][dh][w] = (xp[r * NW + w] - mean) * rstd;
        }
    }
    __syncthreads();

    float acc[CPG];
    const float* bp = bias + b * NC + g * 8;
#pragma unroll
    for (int c = 0; c < CPG; ++c) acc[c] = bp[c];

    const float* wp = weff + (size_t)(b * NC + g * 8) * 72;
    int wm = (w == 0) ? 1 : w - 1;
    int wq = (w == 127) ? 126 : w + 1;

#pragma unroll
    for (int ic = 0; ic < CPG; ++ic) {
        float xv[9];
#pragma unroll
        for (int dh = 0; dh < 3; ++dh) {
            xv[dh * 3 + 0] = sx[ic][dh][wm];
            xv[dh * 3 + 1] = sx[ic][dh][w];
            xv[dh * 3 + 2] = sx[ic][dh][wq];
        }
#pragma unroll
        for (int c = 0; c < CPG; ++c)
#pragma unroll
            for (int t = 0; t < 9; ++t)
                acc[c] += wp[c * 72 + ic * 9 + t] * xv[t];
    }

    unsigned short ob[8];
#pragma unroll
    for (int c = 0; c < CPG; ++c) ob[c] = f2bf(acc[c]);
    uint4 pk;
    pk.x = (unsigned)ob[0] | ((unsigned)ob[1] << 16);
    pk.y = (unsigned)ob[2] | ((unsigned)ob[3] << 16);
    pk.z = (unsigned)ob[4] | ((unsigned)ob[5] << 16);
    pk.w = (unsigned)ob[6] | ((unsigned)ob[7] << 16);
    *(uint4*)(z + ((size_t)((b * NH + h) * NW + w)) * NC + g * 8) = pk;
}

// ---------------------------------------------------------------- final conv (LDS-tiled MFMA implicit GEMM)
// grid 2048: b = id&7 (XCD pin), j = id>>3, nb = j&1 (oc half), h = j>>1.
// block 256 thr / 4 waves, tile 128 w x 128 oc, wave 64x64, BK=64.
// LDS: A 16 KB (single) + B 2x16 KB (double-buffered across taps) = 48 KB.
__global__ __launch_bounds__(256, 3) void final_k(const unsigned short* __restrict__ z,
                                                  const unsigned short* __restrict__ wtT,
                                                  const float* __restrict__ cb,
                                                  float* __restrict__ out) {
    __shared__ s16x8 sAv[1024];        // 128 rows x 8 chunks (16 B), XOR-swizzled
    __shared__ s16x8 sBv[2][1024];

    const int id = blockIdx.x;
    const int b  = id & 7;
    const int jb = id >> 3;
    const int nb = jb & 1;
    const int h  = jb >> 1;

    const int tid  = threadIdx.x;
    const int wv   = tid >> 6;
    const int lane = tid & 63;
    const int l15  = lane & 15;
    const int quad = lane >> 4;
    const int mo   = (wv & 1) << 6;          // w offset of wave tile
    const int nol  = (wv >> 1) << 6;         // oc offset within 128-oc block tile
    const int n0   = (nb << 7) + nol;        // global oc base of wave tile

    // staging: 1024 chunks of 16 B per tile; thread covers chunk it*256+tid.
    // source offset within a [128 rows x 512 B] tile slice (rows stride 512 B,
    // 128 B segment selected by kc added later); XOR-swizzle chunk within segment.
    int srcoff[4], ldsoff[4];
#pragma unroll
    for (int it = 0; it < 4; ++it) {
        int ch  = it * 256 + tid;
        int row = ch >> 3, cp = ch & 7;
        srcoff[it] = row * 512 + ((cp ^ (row & 7)) << 4);
        ldsoff[it] = it * 256 + wv * 64;     // chunk index of wave's uniform base
    }

    // fragment LDS chunk indices (constant over K-loop)
    int aoff[3][4][2];
#pragma unroll
    for (int dw = 0; dw < 3; ++dw)
#pragma unroll
        for (int i = 0; i < 4; ++i) {
            int w_ = refl128(mo + 16 * i + l15 + dw - 1);
#pragma unroll
            for (int kk = 0; kk < 2; ++kk)
                aoff[dw][i][kk] = w_ * 8 + ((kk * 4 + quad) ^ (w_ & 7));
        }
    int boff[4][2];
#pragma unroll
    for (int j = 0; j < 4; ++j) {
        int oc_l = nol + 16 * j + l15;
#pragma unroll
        for (int kk = 0; kk < 2; ++kk)
            boff[j][kk] = oc_l * 8 + ((kk * 4 + quad) ^ (oc_l & 7));
    }

    const char* zb = (const char*)z + (size_t)b * (HWPLANE * NC * 2);   // 8 MB/image
    const char* zr[3];
#pragma unroll
    for (int dh = 0; dh < 3; ++dh)
        zr[dh] = zb + (size_t)refl128(h + dh - 1) * (NW * NC * 2);      // 64 KB/row
    const char* wt = (const char*)wtT + nb * 65536;    // oc-half base; tap stride 131072

    auto stageA = [&](const char* g) {
#pragma unroll
        for (int it = 0; it < 4; ++it)
            async_load16(g + srcoff[it], (void*)(sAv + ldsoff[it]));
    };
    auto stageB = [&](const char* g, int bsel) {
#pragma unroll
        for (int it = 0; it < 4; ++it)
            async_load16(g + srcoff[it], (void*)(sBv[bsel] + ldsoff[it]));
    };

    f32x4 acc[4][4] = {};

    auto compute = [&](const int (&ao)[4][2], int bsel) {
        const s16x8* bbase = sBv[bsel];
#pragma unroll
        for (int kk = 0; kk < 2; ++kk) {
            s16x8 av[4], bv[4];
#pragma unroll
            for (int i = 0; i < 4; ++i) av[i] = sAv[ao[i][kk]];
#pragma unroll
            for (int j = 0; j < 4; ++j) bv[j] = bbase[boff[j][kk]];
#pragma unroll
            for (int i = 0; i < 4; ++i)
#pragma unroll
                for (int j = 0; j < 4; ++j)
                    acc[i][j] = __builtin_amdgcn_mfma_f32_16x16x32_bf16(
                        av[i], bv[j], acc[i][j], 0, 0, 0);
        }
    };

    // K-loop: 12 super-chunks (dh,kc) x 3 taps (dw). B staged one chunk ahead.
    int buf = 0;
    stageA(zr[0]);
    stageB(wt, 0);
    __syncthreads();

    for (int sc = 0; sc < 12; ++sc) {
        const int dh = sc >> 2, kc = sc & 3;
        const char* bt = wt + (size_t)(dh * 3) * 131072 + kc * 128;
        stageB(bt + 131072, buf ^ 1);          // prefetch dw=1
        compute(aoff[0], buf);
        __syncthreads(); buf ^= 1;
        stageB(bt + 262144, buf ^ 1);          // prefetch dw=2
        compute(aoff[1], buf);
        __syncthreads(); buf ^= 1;
        compute(aoff[2], buf);
        __syncthreads();
        if (sc < 11) {                         // stage next (dh,kc): A + first B
            const int sn = sc + 1, dhn = sn >> 2, kcn = sn & 3;
            stageA(zr[dhn] + kcn * 128);
            stageB(wt + (size_t)(dhn * 3) * 131072 + kcn * 128, buf ^ 1);
            __syncthreads();
        }
        buf ^= 1;
    }

    // epilogue: D layout col=lane&15 (oc), row=quad*4+reg (w)
#pragma unroll
    for (int j = 0; j < 4; ++j) {
        int oc = n0 + 16 * j + l15;
        float bvl = cb[oc];
#pragma unroll
        for (int i = 0; i < 4; ++i) {
            int w0 = mo + 16 * i + quad * 4;
            float* dst = out + (((size_t)(b * NOUT + oc) * NH + h) * NW + w0);
            f32x4 v = acc[i][j];
            float4 o4 = { v[0] + bvl, v[1] + bvl, v[2] + bvl, v[3] + bvl };
            *(float4*)dst = o4;
        }
    }
}

// ---------------------------------------------------------------- launch
extern "C" void kernel_launch(void* const* d_in, const int* in_sizes, int n_in,
                              void* d_out, int out_size, void* d_ws, size_t ws_size,
                              hipStream_t stream) {
    const float* x   = (const float*)d_in[0];
    const float* wsp = (const float*)d_in[1];
    const float* wpw = (const float*)d_in[2];
    const float* bia = (const float*)d_in[3];
    const float* cw  = (const float*)d_in[4];
    const float* cb  = (const float*)d_in[5];
    float* out = (float*)d_out;

    // workspace layout (16B aligned):
    //   stats 16 KB | weff 576 KB | wtT 1.13 MB | z 64 MB
    char* ws = (char*)d_ws;
    float*          stats = (float*)ws;                          // 2048*2 f32
    float*          weff  = (float*)(ws + 16384);                // 2048*72 f32
    unsigned short* wtT   = (unsigned short*)(ws + 606208);      // 9*256*256 bf16
    unsigned short* z     = (unsigned short*)(ws + 1785856);     // 8*128*128*256 bf16

    stats_k <<<NB * NC, 256, 0, stream>>>(x, stats);
    weff_k  <<<576,     256, 0, stream>>>(wsp, wpw, weff);
    repack_k<<<2304,    256, 0, stream>>>(cw, wtT);
    ada_k   <<<NB * NG * NH, 128, 0, stream>>>(x, stats, weff, bia, z);
    final_k <<<NB * NH * 2,  256, 0, stream>>>(z, wtT, cb, out);
}

// Round 3
// 433.996 us; speedup vs baseline: 2.1541x; 1.1548x over previous
//
#include <hip/hip_runtime.h>
#include <stdint.h>
#include <stddef.h>

// Problem: AdaConv2d  B=8 C=256 H=W=128 G=32 CPG=8 K=3 OUT=256
// Pipeline: instance-norm -> per-sample adaptive grouped 3x3 (+1x1 grouped +bias)
//           -> static 3x3 conv 256->256, reflect padding everywhere.
//
// final conv = bf16 MFMA implicit GEMM, LDS-tiled (m97 structure), 148us/47% MfmaUtil.
// ada conv  = 8-row-tiled VALU kernel: LDS-staged normalized input, SGPR weights.

typedef __attribute__((ext_vector_type(8))) short   s16x8;  // 8 bf16 in 4 VGPRs
typedef __attribute__((ext_vector_type(4))) float   f32x4;

#define NB   8
#define NC   256
#define NH   128
#define NW   128
#define NG   32
#define CPG  8
#define NOUT 256
#define HWPLANE (NH*NW)          // 16384

__device__ __forceinline__ unsigned short f2bf(float f) {
    union { float f; unsigned u; } v; v.f = f;
    unsigned u = v.u;
    u += 0x7fffu + ((u >> 16) & 1u);   // RNE
    return (unsigned short)(u >> 16);
}

__device__ __forceinline__ int refl128(int i) {
    return i < 0 ? 1 : (i > 127 ? 126 : i);
}

__device__ __forceinline__ void async_load16(const void* g, void* l) {
    __builtin_amdgcn_global_load_lds(
        (const __attribute__((address_space(1))) unsigned int*)g,
        (__attribute__((address_space(3))) unsigned int*)l,
        16, 0, 0);
}

// ---------------------------------------------------------------- stats
__global__ __launch_bounds__(256) void stats_k(const float* __restrict__ x,
                                               float* __restrict__ stats) {
    int bc = blockIdx.x, t = threadIdx.x;
    const float4* p = (const float4*)(x + (size_t)bc * HWPLANE);
    float s = 0.f, q = 0.f;
#pragma unroll
    for (int k = 0; k < 16; ++k) {
        float4 v = p[k * 256 + t];
        s += v.x + v.y + v.z + v.w;
        q += v.x * v.x + v.y * v.y + v.z * v.z + v.w * v.w;
    }
    __shared__ float ss[256], sq[256];
    ss[t] = s; sq[t] = q;
    __syncthreads();
    for (int o = 128; o > 0; o >>= 1) {
        if (t < o) { ss[t] += ss[t + o]; sq[t] += sq[t + o]; }
        __syncthreads();
    }
    if (t == 0) {
        float mean = ss[0] * (1.f / HWPLANE);
        float var  = sq[0] * (1.f / HWPLANE) - mean * mean;
        stats[bc * 2]     = mean;
        stats[bc * 2 + 1] = rsqrtf(var + 1e-5f);
    }
}

// ---------------------------------------------------------------- weff
// weff[bg][ic][tap][oc] = sum_j wp[b, g*8+oc, j] * ws[b, g*8+j, ic, tap]
// layout chosen so the 8 oc-weights of one (ic,tap) are contiguous (s_load_dwordx8)
__global__ __launch_bounds__(256) void weff_k(const float* __restrict__ wsp,
                                              const float* __restrict__ wpw,
                                              float* __restrict__ weff) {
    int tid = blockIdx.x * 256 + threadIdx.x;   // 147456 total, exact
    int oc = tid & 7;
    int q  = tid >> 3;
    int t  = q % 9;
    int q2 = q / 9;
    int ic = q2 & 7;
    int bg = q2 >> 3;                           // b*32+g
    float acc = 0.f;
#pragma unroll
    for (int j = 0; j < 8; ++j)
        acc += wpw[(bg * 8 + oc) * 8 + j] * wsp[((bg * 8 + j) * 8 + ic) * 9 + t];
    weff[(size_t)((bg * 8 + ic) * 9 + t) * 8 + oc] = acc;
}

// ---------------------------------------------------------------- weight repack
// conv_w [O][C][3][3] fp32  ->  wtT [tap][O][C] bf16
__global__ __launch_bounds__(256) void repack_k(const float* __restrict__ cw,
                                                unsigned short* __restrict__ wtT) {
    int tid = blockIdx.x * 256 + threadIdx.x;           // 589824 total, exact
    int c = tid & 255;
    int o = (tid >> 8) & 255;
    int t = tid >> 16;                                  // 0..8
    float v = cw[(size_t)(o * NC + c) * 9 + t];
    wtT[((size_t)t * NOUT + o) * NC + c] = f2bf(v);
}

// ---------------------------------------------------------------- fused norm + adaptive conv
// block = (b, g, h-tile of 8): 256 thr. LDS holds 10 normalized rows x 8 ic (40 KB).
// thread = (w, hq): 4 output rows x 8 oc. Weights are block-uniform -> SGPR loads.
// z written channels-last [B][H][W][C] bf16.
__global__ __launch_bounds__(256) void ada_k(const float* __restrict__ x,
                                             const float* __restrict__ stats,
                                             const float* __restrict__ weff,
                                             const float* __restrict__ bias,
                                             unsigned short* __restrict__ z) {
    __shared__ float sx[CPG][10][NW];       // 40 KB
    const int bx = blockIdx.x;
    const int ht = bx & 15;
    const int g  = (bx >> 4) & 31;
    const int b  = bx >> 9;
    const int h0 = ht * 8;

    // stage + normalize 10 rows x 8 ic (2560 float4 loads, coalesced)
#pragma unroll
    for (int it = 0; it < 10; ++it) {
        int p   = it * 256 + threadIdx.x;   // 0..2559
        int ic  = p / 320;
        int rem = p - ic * 320;
        int row = rem >> 5;
        int w4  = rem & 31;
        int cg  = g * 8 + ic;
        float mean = stats[(b * NC + cg) * 2];
        float rstd = stats[(b * NC + cg) * 2 + 1];
        int rr = refl128(h0 - 1 + row);
        const float4* xp4 = (const float4*)(x + (size_t)(b * NC + cg) * HWPLANE + rr * NW);
        float4 v = xp4[w4];
        float4 n = { (v.x - mean) * rstd, (v.y - mean) * rstd,
                     (v.z - mean) * rstd, (v.w - mean) * rstd };
        *(float4*)&sx[ic][row][w4 * 4] = n;
    }
    __syncthreads();

    const int w  = threadIdx.x & 127;
    const int hq = threadIdx.x >> 7;        // 0/1 -> rows hq*4 .. hq*4+3

    const float* wbase = weff + (size_t)(b * NG + g) * 576;   // block-uniform
    const float* bp    = bias + b * NC + g * 8;               // block-uniform

    float acc[4][8];
#pragma unroll
    for (int r = 0; r < 4; ++r)
#pragma unroll
        for (int oc = 0; oc < 8; ++oc) acc[r][oc] = bp[oc];

#pragma unroll
    for (int ic = 0; ic < CPG; ++ic) {
#pragma unroll
        for (int dw = 0; dw < 3; ++dw) {
            int wc = w + dw - 1;
            wc = wc < 0 ? 1 : (wc > 127 ? 126 : wc);
            float xr[6];
#pragma unroll
            for (int rr = 0; rr < 6; ++rr) xr[rr] = sx[ic][hq * 4 + rr][wc];
#pragma unroll
            for (int dh = 0; dh < 3; ++dh) {
                const float* wv = wbase + (ic * 9 + dh * 3 + dw) * 8;
#pragma unroll
                for (int r = 0; r < 4; ++r)
#pragma unroll
                    for (int oc = 0; oc < 8; ++oc)
                        acc[r][oc] += wv[oc] * xr[r + dh];
            }
        }
    }

#pragma unroll
    for (int r = 0; r < 4; ++r) {
        int h = h0 + hq * 4 + r;
        unsigned short ob[8];
#pragma unroll
        for (int oc = 0; oc < 8; ++oc) ob[oc] = f2bf(acc[r][oc]);
        uint4 pk;
        pk.x = (unsigned)ob[0] | ((unsigned)ob[1] << 16);
        pk.y = (unsigned)ob[2] | ((unsigned)ob[3] << 16);
        pk.z = (unsigned)ob[4] | ((unsigned)ob[5] << 16);
        pk.w = (unsigned)ob[6] | ((unsigned)ob[7] << 16);
        *(uint4*)(z + (size_t)((b * NH + h) * NW + w) * NC + g * 8) = pk;
    }
}

// ---------------------------------------------------------------- final conv (LDS-tiled MFMA implicit GEMM)
// grid 2048: b = id&7 (XCD pin), j = id>>3, nb = j&1 (oc half), h = j>>1.
// block 256 thr / 4 waves, tile 128 w x 128 oc, wave 64x64, BK=64.
// LDS: A 16 KB (single) + B 2x16 KB (double-buffered across taps) = 48 KB.
__global__ __launch_bounds__(256, 3) void final_k(const unsigned short* __restrict__ z,
                                                  const unsigned short* __restrict__ wtT,
                                                  const float* __restrict__ cb,
                                                  float* __restrict__ out) {
    __shared__ s16x8 sAv[1024];        // 128 rows x 8 chunks (16 B), XOR-swizzled
    __shared__ s16x8 sBv[2][1024];

    const int id = blockIdx.x;
    const int b  = id & 7;
    const int jb = id >> 3;
    const int nb = jb & 1;
    const int h  = jb >> 1;

    const int tid  = threadIdx.x;
    const int wv   = tid >> 6;
    const int lane = tid & 63;
    const int l15  = lane & 15;
    const int quad = lane >> 4;
    const int mo   = (wv & 1) << 6;          // w offset of wave tile
    const int nol  = (wv >> 1) << 6;         // oc offset within 128-oc block tile
    const int n0   = (nb << 7) + nol;        // global oc base of wave tile

    int srcoff[4], ldsoff[4];
#pragma unroll
    for (int it = 0; it < 4; ++it) {
        int ch  = it * 256 + tid;
        int row = ch >> 3, cp = ch & 7;
        srcoff[it] = row * 512 + ((cp ^ (row & 7)) << 4);
        ldsoff[it] = it * 256 + wv * 64;     // chunk index of wave's uniform base
    }

    int aoff[3][4][2];
#pragma unroll
    for (int dw = 0; dw < 3; ++dw)
#pragma unroll
        for (int i = 0; i < 4; ++i) {
            int w_ = refl128(mo + 16 * i + l15 + dw - 1);
#pragma unroll
            for (int kk = 0; kk < 2; ++kk)
                aoff[dw][i][kk] = w_ * 8 + ((kk * 4 + quad) ^ (w_ & 7));
        }
    int boff[4][2];
#pragma unroll
    for (int j = 0; j < 4; ++j) {
        int oc_l = nol + 16 * j + l15;
#pragma unroll
        for (int kk = 0; kk < 2; ++kk)
            boff[j][kk] = oc_l * 8 + ((kk * 4 + quad) ^ (oc_l & 7));
    }

    const char* zb = (const char*)z + (size_t)b * (HWPLANE * NC * 2);   // 8 MB/image
    const char* zr[3];
#pragma unroll
    for (int dh = 0; dh < 3; ++dh)
        zr[dh] = zb + (size_t)refl128(h + dh - 1) * (NW * NC * 2);      // 64 KB/row
    const char* wt = (const char*)wtT + nb * 65536;    // oc-half base; tap stride 131072

    auto stageA = [&](const char* g) {
#pragma unroll
        for (int it = 0; it < 4; ++it)
            async_load16(g + srcoff[it], (void*)(sAv + ldsoff[it]));
    };
    auto stageB = [&](const char* g, int bsel) {
#pragma unroll
        for (int it = 0; it < 4; ++it)
            async_load16(g + srcoff[it], (void*)(sBv[bsel] + ldsoff[it]));
    };

    f32x4 acc[4][4] = {};

    auto compute = [&](const int (&ao)[4][2], int bsel) {
        const s16x8* bbase = sBv[bsel];
#pragma unroll
        for (int kk = 0; kk < 2; ++kk) {
            s16x8 av[4], bv[4];
#pragma unroll
            for (int i = 0; i < 4; ++i) av[i] = sAv[ao[i][kk]];
#pragma unroll
            for (int j = 0; j < 4; ++j) bv[j] = bbase[boff[j][kk]];
#pragma unroll
            for (int i = 0; i < 4; ++i)
#pragma unroll
                for (int j = 0; j < 4; ++j)
                    acc[i][j] = __builtin_amdgcn_mfma_f32_16x16x32_bf16(
                        av[i], bv[j], acc[i][j], 0, 0, 0);
        }
    };

    int buf = 0;
    stageA(zr[0]);
    stageB(wt, 0);
    __syncthreads();

    for (int sc = 0; sc < 12; ++sc) {
        const int dh = sc >> 2, kc = sc & 3;
        const char* bt = wt + (size_t)(dh * 3) * 131072 + kc * 128;
        stageB(bt + 131072, buf ^ 1);          // prefetch dw=1
        compute(aoff[0], buf);
        __syncthreads(); buf ^= 1;
        stageB(bt + 262144, buf ^ 1);          // prefetch dw=2
        compute(aoff[1], buf);
        __syncthreads(); buf ^= 1;
        compute(aoff[2], buf);
        __syncthreads();
        if (sc < 11) {                         // stage next (dh,kc): A + first B
            const int sn = sc + 1, dhn = sn >> 2, kcn = sn & 3;
            stageA(zr[dhn] + kcn * 128);
            stageB(wt + (size_t)(dhn * 3) * 131072 + kcn * 128, buf ^ 1);
            __syncthreads();
        }
        buf ^= 1;
    }

    // epilogue: D layout col=lane&15 (oc), row=quad*4+reg (w)
#pragma unroll
    for (int j = 0; j < 4; ++j) {
        int oc = n0 + 16 * j + l15;
        float bvl = cb[oc];
#pragma unroll
        for (int i = 0; i < 4; ++i) {
            int w0 = mo + 16 * i + quad * 4;
            float* dst = out + (((size_t)(b * NOUT + oc) * NH + h) * NW + w0);
            f32x4 v = acc[i][j];
            float4 o4 = { v[0] + bvl, v[1] + bvl, v[2] + bvl, v[3] + bvl };
            *(float4*)dst = o4;
        }
    }
}

// ---------------------------------------------------------------- launch
extern "C" void kernel_launch(void* const* d_in, const int* in_sizes, int n_in,
                              void* d_out, int out_size, void* d_ws, size_t ws_size,
                              hipStream_t stream) {
    const float* x   = (const float*)d_in[0];
    const float* wsp = (const float*)d_in[1];
    const float* wpw = (const float*)d_in[2];
    const float* bia = (const float*)d_in[3];
    const float* cw  = (const float*)d_in[4];
    const float* cb  = (const float*)d_in[5];
    float* out = (float*)d_out;

    // workspace layout (16B aligned):
    //   stats 16 KB | weff 576 KB | wtT 1.13 MB | z 64 MB
    char* ws = (char*)d_ws;
    float*          stats = (float*)ws;                          // 2048*2 f32
    float*          weff  = (float*)(ws + 16384);                // 2048*72 f32
    unsigned short* wtT   = (unsigned short*)(ws + 606208);      // 9*256*256 bf16
    unsigned short* z     = (unsigned short*)(ws + 1785856);     // 8*128*128*256 bf16

    stats_k <<<NB * NC, 256, 0, stream>>>(x, stats);
    weff_k  <<<576,     256, 0, stream>>>(wsp, wpw, weff);
    repack_k<<<2304,    256, 0, stream>>>(cw, wtT);
    ada_k   <<<NB * NG * (NH / 8), 256, 0, stream>>>(x, stats, weff, bia, z);
    final_k <<<NB * NH * 2,  256, 0, stream>>>(z, wtT, cb, out);
}